// Round 1
// baseline (432.971 us; speedup 1.0000x reference)
//
#include <hip/hip_runtime.h>
#include <math.h>

// Problem constants
#define B_SZ   16
#define L_SZ   4096
#define NWIN   4092      // (4096-5)/1+1
#define DIMQ   1024
#define U3     243       // 3^5
#define UPAD   256

// ws layout (float offsets)
#define COS_OFF 0
#define SIN_OFF 131072                    // 16*2*4096
#define Y_OFF   262144
#define M_OFF   (Y_OFF + 1048576)
#define CT_OFF  (M_OFF + 1048576)
#define WS_FLOATS (CT_OFF + U3*UPAD)      // ~2.42M floats = 9.7 MB

// ---------------- trig tables: cos/sin of every x element ----------------
__global__ __launch_bounds__(256) void trig_ker(const float* __restrict__ x,
                                                float* __restrict__ cosT,
                                                float* __restrict__ sinT) {
    int idx = blockIdx.x * 256 + threadIdx.x;   // < 131072
    float v = x[idx];
    cosT[idx] = cosf(v);
    sinT[idx] = sinf(v);
}

// ---------------- Y = (G ⊗ I_512) E,  G = [[c,-s],[-s,-c]], c=cos(th0) ----------------
__global__ __launch_bounds__(256) void y_ker(const float* __restrict__ E,
                                             const float* __restrict__ theta,
                                             float* __restrict__ Y) {
    int idx = blockIdx.x * 256 + threadIdx.x;   // < 524288
    float th = theta[0];
    float st, ct;
    __sincosf(th, &st, &ct);
    int r = idx >> 10, k = idx & 1023;
    float e0 = E[r * 1024 + k];
    float e1 = E[(512 + r) * 1024 + k];
    Y[r * 1024 + k]        =  ct * e0 - st * e1;
    Y[(512 + r) * 1024 + k] = -st * e0 - ct * e1;
}

// ---------------- M = E^T Y  (1024x1024x1024 fp32 GEMM, 64x64 tiles) ----------------
__global__ __launch_bounds__(256) void mgemm_ker(const float* __restrict__ E,
                                                 const float* __restrict__ Y,
                                                 float* __restrict__ M) {
    __shared__ float Es[16 * 64];
    __shared__ float Ys[16 * 64];
    int bj = blockIdx.x, bk = blockIdx.y;
    int tid = threadIdx.x;
    int tx = tid & 15, ty = tid >> 4;
    float acc[4][4] = {{0.f,0.f,0.f,0.f},{0.f,0.f,0.f,0.f},{0.f,0.f,0.f,0.f},{0.f,0.f,0.f,0.f}};
    for (int d0 = 0; d0 < 1024; d0 += 16) {
        #pragma unroll
        for (int k = 0; k < 4; ++k) {
            int idx = tid + k * 256;
            int dd = idx >> 6, jj = idx & 63;
            Es[idx] = E[(d0 + dd) * 1024 + bj * 64 + jj];
            Ys[idx] = Y[(d0 + dd) * 1024 + bk * 64 + jj];
        }
        __syncthreads();
        #pragma unroll
        for (int dd = 0; dd < 16; ++dd) {
            float4 a = ((const float4*)Es)[dd * 16 + ty];
            float4 b = ((const float4*)Ys)[dd * 16 + tx];
            acc[0][0] += a.x * b.x; acc[0][1] += a.x * b.y; acc[0][2] += a.x * b.z; acc[0][3] += a.x * b.w;
            acc[1][0] += a.y * b.x; acc[1][1] += a.y * b.y; acc[1][2] += a.y * b.z; acc[1][3] += a.y * b.w;
            acc[2][0] += a.z * b.x; acc[2][1] += a.z * b.y; acc[2][2] += a.z * b.z; acc[2][3] += a.z * b.w;
            acc[3][0] += a.w * b.x; acc[3][1] += a.w * b.y; acc[3][2] += a.w * b.z; acc[3][3] += a.w * b.w;
        }
        __syncthreads();
    }
    #pragma unroll
    for (int i = 0; i < 4; ++i) {
        float4 r = make_float4(acc[i][0], acc[i][1], acc[i][2], acc[i][3]);
        *(float4*)(M + (bj * 64 + ty * 4 + i) * 1024 + bk * 64 + tx * 4) = r;
    }
}

// ---------------- C[t] = 2^-10 sum_j (-1)^{pc(j&mz)} M[j, j^mx]  via WHT ----------------
// one block per mx; output layout CT[v*256 + u] (u = ch0 digits, v = ch1 digits)
__global__ __launch_bounds__(256) void cwht_ker(const float* __restrict__ M,
                                                float* __restrict__ CT) {
    __shared__ float D[1024];
    int mx = blockIdx.x;
    int tid = threadIdx.x;
    #pragma unroll
    for (int k = 0; k < 4; ++k) {
        int j = tid + k * 256;
        D[j] = M[j * 1024 + (j ^ mx)];
    }
    __syncthreads();
    for (int s = 0; s < 10; ++s) {
        #pragma unroll
        for (int k = 0; k < 2; ++k) {
            int p = tid + k * 256;            // 512 butterflies
            int i = ((p >> s) << (s + 1)) | (p & ((1 << s) - 1));
            int j2 = i | (1 << s);
            float lo = D[i], hi = D[j2];
            D[i] = lo + hi;
            D[j2] = lo - hi;
        }
        __syncthreads();
    }
    for (int mz = tid; mz < 1024; mz += 256) {
        if (mz & mx) continue;
        int u = 0, v = 0;
        #pragma unroll
        for (int i = 0; i < 5; ++i) {
            int bit = 9 - i;
            int t = ((mx >> bit) & 1) ? 2 : (((mz >> bit) & 1) ? 1 : 0);
            u = u * 3 + t;
        }
        #pragma unroll
        for (int i = 5; i < 10; ++i) {
            int bit = 9 - i;
            int t = ((mx >> bit) & 1) ? 2 : (((mz >> bit) & 1) ? 1 : 0);
            v = v * 3 + t;
        }
        CT[v * UPAD + u] = D[mz] * (1.0f / 1024.0f);
    }
    // zero the u-padding columns (u in [243,256)) once, using block mx==0
    if (mx == 0) {
        for (int e = tid; e < U3 * (UPAD - U3); e += 256) {
            int v = e / (UPAD - U3), q = e % (UPAD - U3);
            CT[v * UPAD + U3 + q] = 0.0f;
        }
    }
}

// ---------------- main: z[n] = F0(n)^T C F1(n), 64 windows per block ----------------
__global__ __launch_bounds__(256, 2) void main_ker(const float* __restrict__ cosT,
                                                   const float* __restrict__ sinT,
                                                   const float* __restrict__ CT,
                                                   float* __restrict__ out) {
    __shared__ float Ft[U3 * 64];     // F1 tile then F0 tile, [idx = slot*64 + w]
    __shared__ float fT[3][68];       // per-position features 1/cos/sin
    __shared__ float partial[4][64];
    int w0 = blockIdx.x * 64;
    int b = blockIdx.y;
    int nwin = (NWIN - w0 < 64) ? (NWIN - w0) : 64;
    int tid = threadIdx.x;

    // ---- channel-1 trig ----
    for (int p = tid; p < 68; p += 256) {
        int l = w0 + p;
        bool ok = l < L_SZ;
        fT[0][p] = 1.0f;
        fT[1][p] = ok ? cosT[b * 8192 + 4096 + l] : 0.0f;
        fT[2][p] = ok ? sinT[b * 8192 + 4096 + l] : 0.0f;
    }
    __syncthreads();
    // ---- build F1 tile: Ft[v*64+w] = prod_k fT[digit_k(v)][w+k] ----
    for (int idx = tid; idx < U3 * 64; idx += 256) {
        int v = idx >> 6, w = idx & 63;
        int t0 = v / 81, r = v - t0 * 81;
        int t1 = r / 27; r -= t1 * 27;
        int t2 = r / 9;  r -= t2 * 9;
        int t3 = r / 3;  int t4 = r - t3 * 3;
        Ft[idx] = fT[t0][w] * fT[t1][w + 1] * fT[t2][w + 2] * fT[t3][w + 3] * fT[t4][w + 4];
    }
    __syncthreads();

    // ---- GEMM phase: thread owns u=tid; acc[w] = sum_v C[u,v] * F1[w,v] ----
    float acc[64];
    #pragma unroll
    for (int w = 0; w < 64; ++w) acc[w] = 0.0f;
    {
        const float4* F4 = (const float4*)Ft;
        #pragma unroll 3
        for (int v = 0; v < U3; ++v) {
            float cu = CT[v * UPAD + tid];          // zero for tid >= 243
            const float4* row = F4 + v * 16;
            #pragma unroll
            for (int q = 0; q < 16; ++q) {
                float4 f = row[q];
                acc[q * 4 + 0] += cu * f.x;
                acc[q * 4 + 1] += cu * f.y;
                acc[q * 4 + 2] += cu * f.z;
                acc[q * 4 + 3] += cu * f.w;
            }
        }
    }
    __syncthreads();

    // ---- channel-0 trig ----
    for (int p = tid; p < 68; p += 256) {
        int l = w0 + p;
        bool ok = l < L_SZ;
        fT[1][p] = ok ? cosT[b * 8192 + l] : 0.0f;
        fT[2][p] = ok ? sinT[b * 8192 + l] : 0.0f;
    }
    __syncthreads();
    // ---- build F0 tile: Ft[u*64+w] ----
    for (int idx = tid; idx < U3 * 64; idx += 256) {
        int u = idx >> 6, w = idx & 63;
        int t0 = u / 81, r = u - t0 * 81;
        int t1 = r / 27; r -= t1 * 27;
        int t2 = r / 9;  r -= t2 * 9;
        int t3 = r / 3;  int t4 = r - t3 * 3;
        Ft[idx] = fT[t0][w] * fT[t1][w + 1] * fT[t2][w + 2] * fT[t3][w + 3] * fT[t4][w + 4];
    }
    __syncthreads();

    // ---- scale by F0[u,w] (zero for pad threads), reduce over u across block ----
    if (tid < U3) {
        const float4* row = ((const float4*)Ft) + tid * 16;
        #pragma unroll
        for (int q = 0; q < 16; ++q) {
            float4 f = row[q];
            acc[q * 4 + 0] *= f.x;
            acc[q * 4 + 1] *= f.y;
            acc[q * 4 + 2] *= f.z;
            acc[q * 4 + 3] *= f.w;
        }
    } else {
        #pragma unroll
        for (int w = 0; w < 64; ++w) acc[w] = 0.0f;
    }
    int wave = tid >> 6, lane = tid & 63;
    #pragma unroll
    for (int w = 0; w < 64; ++w) {
        float val = acc[w];
        #pragma unroll
        for (int off = 32; off; off >>= 1) val += __shfl_xor(val, off, 64);
        if (lane == w) partial[wave][w] = val;
    }
    __syncthreads();
    if (tid < 64) {
        int w = tid;
        if (w < nwin) {
            float z = partial[0][w] + partial[1][w] + partial[2][w] + partial[3][w];
            out[b * NWIN + w0 + w] = z;
        }
    }
}

extern "C" void kernel_launch(void* const* d_in, const int* in_sizes, int n_in,
                              void* d_out, int out_size, void* d_ws, size_t ws_size,
                              hipStream_t stream) {
    const float* x     = (const float*)d_in[0];   // (16,2,4096)
    const float* E     = (const float*)d_in[1];   // (1024,1024)
    const float* theta = (const float*)d_in[2];   // (10,)
    float* out = (float*)d_out;                   // (16,1,1,4092) -> 65472
    float* ws = (float*)d_ws;

    float* cosT = ws + COS_OFF;
    float* sinT = ws + SIN_OFF;
    float* Y    = ws + Y_OFF;
    float* M    = ws + M_OFF;
    float* CT   = ws + CT_OFF;

    trig_ker<<<512, 256, 0, stream>>>(x, cosT, sinT);
    y_ker<<<2048, 256, 0, stream>>>(E, theta, Y);
    mgemm_ker<<<dim3(16, 16), 256, 0, stream>>>(E, Y, M);
    cwht_ker<<<1024, 256, 0, stream>>>(M, CT);
    main_ker<<<dim3(64, 16), 256, 0, stream>>>(cosT, sinT, CT, out);
}

// Round 2
// 351.593 us; speedup vs baseline: 1.2315x; 1.2315x over previous
//
#include <hip/hip_runtime.h>
#include <math.h>

// Problem constants
#define B_SZ   16
#define L_SZ   4096
#define NWIN   4092      // (4096-5)/1+1
#define U3     243       // 3^5
#define UPAD   256

// ws layout (float offsets)
#define COS_OFF 0
#define SIN_OFF 131072                    // 16*2*4096
#define Y_OFF   262144
#define M_OFF   (Y_OFF + 1048576)
#define CT_OFF  (M_OFF + 1048576)
#define WS_FLOATS (CT_OFF + 256*256)

__device__ __forceinline__ float sel3(int t, float c, float s) {
    return t == 0 ? 1.0f : (t == 1 ? c : s);
}

// ---------------- trig tables ----------------
__global__ __launch_bounds__(256) void trig_ker(const float* __restrict__ x,
                                                float* __restrict__ cosT,
                                                float* __restrict__ sinT) {
    int idx = blockIdx.x * 256 + threadIdx.x;   // < 131072
    float v = x[idx];
    cosT[idx] = cosf(v);
    sinT[idx] = sinf(v);
}

// ---------------- Y = (G ⊗ I_512) E ----------------
__global__ __launch_bounds__(256) void y_ker(const float* __restrict__ E,
                                             const float* __restrict__ theta,
                                             float* __restrict__ Y) {
    int idx = blockIdx.x * 256 + threadIdx.x;   // < 524288
    float th = theta[0];
    float st, ct;
    __sincosf(th, &st, &ct);
    int r = idx >> 10, k = idx & 1023;
    float e0 = E[r * 1024 + k];
    float e1 = E[(512 + r) * 1024 + k];
    Y[r * 1024 + k]         =  ct * e0 - st * e1;
    Y[(512 + r) * 1024 + k] = -st * e0 - ct * e1;
}

// ---------------- zero M ----------------
__global__ __launch_bounds__(256) void zero_ker(float* __restrict__ M) {
    int i = blockIdx.x * 256 + threadIdx.x;     // < 262144 float4
    ((float4*)M)[i] = make_float4(0.f, 0.f, 0.f, 0.f);
}

// ---------------- M = E^T Y, K-split 4, 128x128 tile, 8x8 thread tile ----------------
__global__ __launch_bounds__(256) void mgemm_ker(const float* __restrict__ E,
                                                 const float* __restrict__ Y,
                                                 float* __restrict__ M) {
    __shared__ float Es[16][128];
    __shared__ float Ys[16][128];   // chunk-swizzled
    int bj = blockIdx.x, bk = blockIdx.y, ks = blockIdx.z;
    int tid = threadIdx.x;
    int tx = tid & 15, ty = tid >> 4;
    int lrow = tid >> 4, lcol = (tid & 15) * 8;
    float acc[8][8];
    #pragma unroll
    for (int i = 0; i < 8; ++i)
        #pragma unroll
        for (int j = 0; j < 8; ++j) acc[i][j] = 0.f;

    int cw0 = lcol >> 2, cw1 = cw0 + 1;
    int pw0 = cw0 ^ (cw0 >> 3), pw1 = cw1 ^ (cw1 >> 3);
    int ca = tx * 2, cb = ca + 1;
    int pa = ca ^ (ca >> 3), pb = cb ^ (cb >> 3);

    for (int d0 = ks * 256; d0 < ks * 256 + 256; d0 += 16) {
        float4 e0 = *(const float4*)&E[(d0 + lrow) * 1024 + bj * 128 + lcol];
        float4 e1 = *(const float4*)&E[(d0 + lrow) * 1024 + bj * 128 + lcol + 4];
        float4 y0 = *(const float4*)&Y[(d0 + lrow) * 1024 + bk * 128 + lcol];
        float4 y1 = *(const float4*)&Y[(d0 + lrow) * 1024 + bk * 128 + lcol + 4];
        __syncthreads();
        *(float4*)&Es[lrow][lcol] = e0;
        *(float4*)&Es[lrow][lcol + 4] = e1;
        *(float4*)&Ys[lrow][pw0 * 4] = y0;
        *(float4*)&Ys[lrow][pw1 * 4] = y1;
        __syncthreads();
        #pragma unroll
        for (int dd = 0; dd < 16; ++dd) {
            float4 a0 = *(const float4*)&Es[dd][ty * 8];
            float4 a1 = *(const float4*)&Es[dd][ty * 8 + 4];
            float4 b0 = *(const float4*)&Ys[dd][pa * 4];
            float4 b1 = *(const float4*)&Ys[dd][pb * 4];
            float av[8] = {a0.x, a0.y, a0.z, a0.w, a1.x, a1.y, a1.z, a1.w};
            float bv[8] = {b0.x, b0.y, b0.z, b0.w, b1.x, b1.y, b1.z, b1.w};
            #pragma unroll
            for (int i = 0; i < 8; ++i)
                #pragma unroll
                for (int j = 0; j < 8; ++j) acc[i][j] += av[i] * bv[j];
        }
    }
    #pragma unroll
    for (int i = 0; i < 8; ++i)
        #pragma unroll
        for (int j = 0; j < 8; ++j)
            atomicAdd(&M[(bj * 128 + ty * 8 + i) * 1024 + bk * 128 + tx * 8 + j], acc[i][j]);
}

// ---------------- C via WHT of generalized diagonals ----------------
__global__ __launch_bounds__(256) void cwht_ker(const float* __restrict__ M,
                                                float* __restrict__ CT) {
    __shared__ float D[1024];
    int mx = blockIdx.x;
    int tid = threadIdx.x;
    #pragma unroll
    for (int k = 0; k < 4; ++k) {
        int j = tid + k * 256;
        D[j] = M[j * 1024 + (j ^ mx)];
    }
    __syncthreads();
    for (int s = 0; s < 10; ++s) {
        #pragma unroll
        for (int k = 0; k < 2; ++k) {
            int p = tid + k * 256;
            int i = ((p >> s) << (s + 1)) | (p & ((1 << s) - 1));
            int j2 = i | (1 << s);
            float lo = D[i], hi = D[j2];
            D[i] = lo + hi;
            D[j2] = lo - hi;
        }
        __syncthreads();
    }
    for (int mz = tid; mz < 1024; mz += 256) {
        if (mz & mx) continue;
        int u = 0, v = 0;
        #pragma unroll
        for (int i = 0; i < 5; ++i) {
            int bit = 9 - i;
            int t = ((mx >> bit) & 1) ? 2 : (((mz >> bit) & 1) ? 1 : 0);
            u = u * 3 + t;
        }
        #pragma unroll
        for (int i = 5; i < 10; ++i) {
            int bit = 9 - i;
            int t = ((mx >> bit) & 1) ? 2 : (((mz >> bit) & 1) ? 1 : 0);
            v = v * 3 + t;
        }
        CT[v * UPAD + u] = D[mz] * (1.0f / 1024.0f);
    }
    if (mx == 0) {
        // zero u-padding columns for valid v rows
        for (int e = tid; e < U3 * (UPAD - U3); e += 256) {
            int v = e / (UPAD - U3), q = e % (UPAD - U3);
            CT[v * UPAD + U3 + q] = 0.0f;
        }
        // zero v rows 243..255 entirely (main loop iterates v to 255)
        for (int e = tid; e < (256 - U3) * UPAD; e += 256) {
            CT[U3 * UPAD + e] = 0.0f;
        }
    }
}

// ---------------- main: per block 128 windows, G = C x F1 reg-tiled, F0 epilogue ----------------
// thread tile: 16u x 8w; a-frags from global CT (L2), b-frags from 8KB swizzled LDS chunk
__global__ __launch_bounds__(256, 2) void main_ker(const float* __restrict__ cosT,
                                                   const float* __restrict__ sinT,
                                                   const float* __restrict__ CT,
                                                   float* __restrict__ out) {
    __shared__ float F1c[16 * 128];        // [v_local][swizzled w]
    __shared__ float partial[4][16][8];
    int tid = threadIdx.x;
    int w0 = blockIdx.x * 128;
    int b = blockIdx.y;
    int tx = tid & 15, ty = tid >> 4;

    // build-role trig registers (channel 1) at fixed per-thread position wb
    int wb = tid & 127;
    int vh = tid >> 7;                     // builds v_local in [vh*8, vh*8+8)
    float c1[5], s1[5];
    {
        const float* cos1 = cosT + b * 8192 + 4096;
        const float* sin1 = sinT + b * 8192 + 4096;
        #pragma unroll
        for (int k = 0; k < 5; ++k) {
            int pos = w0 + wb + k;
            bool ok = pos < L_SZ;
            c1[k] = ok ? cos1[pos] : 0.f;
            s1[k] = ok ? sin1[pos] : 0.f;
        }
    }
    // swizzled store slot for this thread's build column
    int cb_ = wb >> 2;
    int pb_ = cb_ ^ (cb_ >> 3);
    int bslot = pb_ * 4 + (wb & 3);
    // swizzled read chunks for this thread's b-frag
    int c0_ = tx * 2, c1_ = tx * 2 + 1;
    int rp0 = c0_ ^ (c0_ >> 3), rp1 = c1_ ^ (c1_ >> 3);

    float acc[16][8];
    #pragma unroll
    for (int i = 0; i < 16; ++i)
        #pragma unroll
        for (int j = 0; j < 8; ++j) acc[i][j] = 0.f;

    #pragma unroll 1
    for (int ch = 0; ch < 16; ++ch) {
        __syncthreads();
        // build 8 F1 entries (fixed w = wb, v_local = vh*8 + vv)
        #pragma unroll
        for (int vv = 0; vv < 8; ++vv) {
            int vg = ch * 16 + vh * 8 + vv;
            int t0 = vg / 81; int r = vg - t0 * 81;
            int t1 = r / 27; r -= t1 * 27;
            int t2 = r / 9;  r -= t2 * 9;
            int t3 = r / 3;  int t4 = r - t3 * 3;
            float val = sel3(t0, c1[0], s1[0]) * sel3(t1, c1[1], s1[1]) * sel3(t2, c1[2], s1[2])
                      * sel3(t3, c1[3], s1[3]) * sel3(t4, c1[4], s1[4]);
            F1c[(vh * 8 + vv) * 128 + bslot] = val;
        }
        __syncthreads();
        // GEMM over this v-chunk
        #pragma unroll 2
        for (int vv = 0; vv < 16; ++vv) {
            int vg = ch * 16 + vv;
            const float4* arow = (const float4*)&CT[vg * UPAD + ty * 16];
            float4 a0 = arow[0], a1 = arow[1], a2 = arow[2], a3 = arow[3];
            float4 b0 = *(const float4*)&F1c[vv * 128 + rp0 * 4];
            float4 b1 = *(const float4*)&F1c[vv * 128 + rp1 * 4];
            float av[16] = {a0.x, a0.y, a0.z, a0.w, a1.x, a1.y, a1.z, a1.w,
                            a2.x, a2.y, a2.z, a2.w, a3.x, a3.y, a3.z, a3.w};
            float bv[8] = {b0.x, b0.y, b0.z, b0.w, b1.x, b1.y, b1.z, b1.w};
            #pragma unroll
            for (int i = 0; i < 16; ++i)
                #pragma unroll
                for (int j = 0; j < 8; ++j) acc[i][j] += av[i] * bv[j];
        }
    }

    // ---- epilogue: scale by F0 (built from registers), reduce over u ----
    float c0r[12], s0r[12];
    {
        const float* cos0 = cosT + b * 8192;
        const float* sin0 = sinT + b * 8192;
        #pragma unroll
        for (int p = 0; p < 12; ++p) {
            int pos = w0 + tx * 8 + p;
            bool ok = pos < L_SZ;
            c0r[p] = ok ? cos0[pos] : 0.f;
            s0r[p] = ok ? sin0[pos] : 0.f;
        }
    }
    float zs[8];
    #pragma unroll
    for (int j = 0; j < 8; ++j) zs[j] = 0.f;
    int u0 = ty * 16;
    #pragma unroll
    for (int i = 0; i < 16; ++i) {
        int u = u0 + i;
        int t0 = u / 81; int r = u - t0 * 81;
        int t1 = r / 27; r -= t1 * 27;
        int t2 = r / 9;  r -= t2 * 9;
        int t3 = r / 3;  int t4 = r - t3 * 3;
        #pragma unroll
        for (int j = 0; j < 8; ++j) {
            float f = sel3(t0, c0r[j], s0r[j]) * sel3(t1, c0r[j + 1], s0r[j + 1])
                    * sel3(t2, c0r[j + 2], s0r[j + 2]) * sel3(t3, c0r[j + 3], s0r[j + 3])
                    * sel3(t4, c0r[j + 4], s0r[j + 4]);
            zs[j] += f * acc[i][j];
        }
    }
    // reduce over ty: in-wave (ty&3 via lanes 16,32), then cross-wave via LDS
    #pragma unroll
    for (int j = 0; j < 8; ++j) {
        float v = zs[j];
        v += __shfl_xor(v, 16, 64);
        v += __shfl_xor(v, 32, 64);
        zs[j] = v;
    }
    int wave = tid >> 6, lane = tid & 63;
    if (lane < 16) {
        #pragma unroll
        for (int j = 0; j < 8; ++j) partial[wave][lane][j] = zs[j];
    }
    __syncthreads();
    if (tid < 128) {
        int wo = tid;
        float z = partial[0][wo >> 3][wo & 7] + partial[1][wo >> 3][wo & 7]
                + partial[2][wo >> 3][wo & 7] + partial[3][wo >> 3][wo & 7];
        if (w0 + wo < NWIN) out[b * NWIN + w0 + wo] = z;
    }
}

extern "C" void kernel_launch(void* const* d_in, const int* in_sizes, int n_in,
                              void* d_out, int out_size, void* d_ws, size_t ws_size,
                              hipStream_t stream) {
    const float* x     = (const float*)d_in[0];
    const float* E     = (const float*)d_in[1];
    const float* theta = (const float*)d_in[2];
    float* out = (float*)d_out;
    float* ws = (float*)d_ws;

    float* cosT = ws + COS_OFF;
    float* sinT = ws + SIN_OFF;
    float* Y    = ws + Y_OFF;
    float* M    = ws + M_OFF;
    float* CT   = ws + CT_OFF;

    trig_ker<<<512, 256, 0, stream>>>(x, cosT, sinT);
    y_ker<<<2048, 256, 0, stream>>>(E, theta, Y);
    zero_ker<<<1024, 256, 0, stream>>>(M);
    mgemm_ker<<<dim3(8, 8, 4), 256, 0, stream>>>(E, Y, M);
    cwht_ker<<<1024, 256, 0, stream>>>(M, CT);
    main_ker<<<dim3(32, 16), 256, 0, stream>>>(cosT, sinT, CT, out);
}

// Round 3
// 219.853 us; speedup vs baseline: 1.9694x; 1.5992x over previous
//
#include <hip/hip_runtime.h>
#include <math.h>

// Problem constants
#define B_SZ   16
#define L_SZ   4096
#define NWIN   4092      // (4096-5)/1+1
#define U3     243       // 3^5
#define UPAD   256

// ws layout (float offsets)
#define COS_OFF 0
#define SIN_OFF 131072                    // 16*2*4096
#define Y_OFF   262144
#define M_OFF   (Y_OFF + 1048576)         // 1310720
#define CT_OFF  (M_OFF + 1048576)         // 2359296
#define EXTRA_OFF (CT_OFF + 65536)        // 2424832  (K-split partial buffers)

__device__ __forceinline__ float sel3(int t, float c, float s) {
    return t == 0 ? 1.0f : (t == 1 ? c : s);
}

// ---------------- trig tables ----------------
__global__ __launch_bounds__(256) void trig_ker(const float* __restrict__ x,
                                                float* __restrict__ cosT,
                                                float* __restrict__ sinT) {
    int idx = blockIdx.x * 256 + threadIdx.x;   // < 131072
    float v = x[idx];
    cosT[idx] = cosf(v);
    sinT[idx] = sinf(v);
}

// ---------------- Y = (G ⊗ I_512) E ----------------
__global__ __launch_bounds__(256) void y_ker(const float* __restrict__ E,
                                             const float* __restrict__ theta,
                                             float* __restrict__ Y) {
    int idx = blockIdx.x * 256 + threadIdx.x;   // < 524288
    float th = theta[0];
    float st, ct;
    __sincosf(th, &st, &ct);
    int r = idx >> 10, k = idx & 1023;
    float e0 = E[r * 1024 + k];
    float e1 = E[(512 + r) * 1024 + k];
    Y[r * 1024 + k]         =  ct * e0 - st * e1;
    Y[(512 + r) * 1024 + k] = -st * e0 - ct * e1;
}

// ---------------- M = E^T Y, K-split S into separate partials (no atomics) ----------------
// grid (16,16,S); 64x64 tile, 4x4 thread tile; a-frag is a 16-lane LDS broadcast (free)
__global__ __launch_bounds__(256, 2) void mgemm_ker(const float* __restrict__ E,
                                                    const float* __restrict__ Y,
                                                    float* __restrict__ M,
                                                    float* __restrict__ Mp_extra) {
    __shared__ float Es[16][64];
    __shared__ float Ys[16][64];
    int bj = blockIdx.x, bk = blockIdx.y, ks = blockIdx.z;
    int S = gridDim.z;
    int tid = threadIdx.x;
    int tx = tid & 15, ty = tid >> 4;
    int lr = tid >> 4, lc = (tid & 15) * 4;
    float acc[4][4];
    #pragma unroll
    for (int i = 0; i < 4; ++i)
        #pragma unroll
        for (int j = 0; j < 4; ++j) acc[i][j] = 0.f;

    int kchunk = 1024 / S;
    int k0 = ks * kchunk;
    for (int d0 = k0; d0 < k0 + kchunk; d0 += 16) {
        float4 e = *(const float4*)&E[(d0 + lr) * 1024 + bj * 64 + lc];
        float4 y = *(const float4*)&Y[(d0 + lr) * 1024 + bk * 64 + lc];
        __syncthreads();
        *(float4*)&Es[lr][lc] = e;
        *(float4*)&Ys[lr][lc] = y;
        __syncthreads();
        #pragma unroll
        for (int dd = 0; dd < 16; ++dd) {
            float4 a = *(const float4*)&Es[dd][ty * 4];   // broadcast across 16 lanes
            float4 bv = *(const float4*)&Ys[dd][tx * 4];
            acc[0][0] += a.x * bv.x; acc[0][1] += a.x * bv.y; acc[0][2] += a.x * bv.z; acc[0][3] += a.x * bv.w;
            acc[1][0] += a.y * bv.x; acc[1][1] += a.y * bv.y; acc[1][2] += a.y * bv.z; acc[1][3] += a.y * bv.w;
            acc[2][0] += a.z * bv.x; acc[2][1] += a.z * bv.y; acc[2][2] += a.z * bv.z; acc[2][3] += a.z * bv.w;
            acc[3][0] += a.w * bv.x; acc[3][1] += a.w * bv.y; acc[3][2] += a.w * bv.z; acc[3][3] += a.w * bv.w;
        }
    }
    float* dst = (ks == 0) ? M : (Mp_extra + (ks - 1) * 1048576);
    #pragma unroll
    for (int i = 0; i < 4; ++i) {
        float4 r = make_float4(acc[i][0], acc[i][1], acc[i][2], acc[i][3]);
        *(float4*)&dst[(bj * 64 + ty * 4 + i) * 1024 + bk * 64 + tx * 4] = r;
    }
}

// ---------------- sum partials into M (in place, M == partial 0) ----------------
__global__ __launch_bounds__(256) void sum_ker(float* __restrict__ M,
                                               const float* __restrict__ Mp_extra,
                                               int S) {
    int i = blockIdx.x * 256 + threadIdx.x;   // < 262144 float4
    float4 v = ((const float4*)M)[i];
    for (int s = 1; s < S; ++s) {
        float4 p = ((const float4*)(Mp_extra + (s - 1) * 1048576))[i];
        v.x += p.x; v.y += p.y; v.z += p.z; v.w += p.w;
    }
    ((float4*)M)[i] = v;
}

// ---------------- C via WHT of generalized diagonals ----------------
__global__ __launch_bounds__(256) void cwht_ker(const float* __restrict__ M,
                                                float* __restrict__ CT) {
    __shared__ float D[1024];
    int mx = blockIdx.x;
    int tid = threadIdx.x;
    #pragma unroll
    for (int k = 0; k < 4; ++k) {
        int j = tid + k * 256;
        D[j] = M[j * 1024 + (j ^ mx)];
    }
    __syncthreads();
    for (int s = 0; s < 10; ++s) {
        #pragma unroll
        for (int k = 0; k < 2; ++k) {
            int p = tid + k * 256;
            int i = ((p >> s) << (s + 1)) | (p & ((1 << s) - 1));
            int j2 = i | (1 << s);
            float lo = D[i], hi = D[j2];
            D[i] = lo + hi;
            D[j2] = lo - hi;
        }
        __syncthreads();
    }
    for (int mz = tid; mz < 1024; mz += 256) {
        if (mz & mx) continue;
        int u = 0, v = 0;
        #pragma unroll
        for (int i = 0; i < 5; ++i) {
            int bit = 9 - i;
            int t = ((mx >> bit) & 1) ? 2 : (((mz >> bit) & 1) ? 1 : 0);
            u = u * 3 + t;
        }
        #pragma unroll
        for (int i = 5; i < 10; ++i) {
            int bit = 9 - i;
            int t = ((mx >> bit) & 1) ? 2 : (((mz >> bit) & 1) ? 1 : 0);
            v = v * 3 + t;
        }
        CT[v * UPAD + u] = D[mz] * (1.0f / 1024.0f);
    }
    if (mx == 0) {
        for (int e = tid; e < U3 * (UPAD - U3); e += 256) {
            int v = e / (UPAD - U3), q = e % (UPAD - U3);
            CT[v * UPAD + U3 + q] = 0.0f;
        }
        for (int e = tid; e < (256 - U3) * UPAD; e += 256) {
            CT[U3 * UPAD + e] = 0.0f;
        }
    }
}

// ---------------- main: 64 windows/block, thread tile 16u x 4w ----------------
// a-frags: 4x float4 from global CT (L2, 16-lane broadcast); b-frag: 1x b128 from LDS
__global__ __launch_bounds__(256, 3) void main_ker(const float* __restrict__ cosT,
                                                   const float* __restrict__ sinT,
                                                   const float* __restrict__ CT,
                                                   float* __restrict__ out) {
    __shared__ float F1c[16 * 64];       // [vv][w]
    __shared__ float partial[4][16][4];
    int tid = threadIdx.x;
    int w0 = blockIdx.x * 64;
    int b = blockIdx.y;
    int tx = tid & 15, ty = tid >> 4;

    // builder role: thread owns column wb, builds 4 vv rows per chunk
    int wb = tid & 63;
    int vvb = (tid >> 6) * 4;
    float c1[5], s1[5];
    {
        const float* cos1 = cosT + b * 8192 + 4096;
        const float* sin1 = sinT + b * 8192 + 4096;
        #pragma unroll
        for (int k = 0; k < 5; ++k) {
            int pos = w0 + wb + k;
            bool ok = pos < L_SZ;
            c1[k] = ok ? cos1[pos] : 0.f;
            s1[k] = ok ? sin1[pos] : 0.f;
        }
    }

    float acc[16][4];
    #pragma unroll
    for (int i = 0; i < 16; ++i)
        #pragma unroll
        for (int j = 0; j < 4; ++j) acc[i][j] = 0.f;

    #pragma unroll 1
    for (int ch = 0; ch < 16; ++ch) {
        __syncthreads();
        #pragma unroll
        for (int q = 0; q < 4; ++q) {
            int vv = vvb + q;
            int vg = ch * 16 + vv;
            int t0 = vg / 81; int r = vg - t0 * 81;
            int t1 = r / 27; r -= t1 * 27;
            int t2 = r / 9;  r -= t2 * 9;
            int t3 = r / 3;  int t4 = r - t3 * 3;
            F1c[vv * 64 + wb] = sel3(t0, c1[0], s1[0]) * sel3(t1, c1[1], s1[1])
                              * sel3(t2, c1[2], s1[2]) * sel3(t3, c1[3], s1[3])
                              * sel3(t4, c1[4], s1[4]);
        }
        __syncthreads();
        #pragma unroll 2
        for (int vv = 0; vv < 16; ++vv) {
            int vg = ch * 16 + vv;
            const float4* arow = (const float4*)&CT[vg * UPAD + ty * 16];
            float4 a0 = arow[0], a1 = arow[1], a2 = arow[2], a3 = arow[3];
            float4 f = *(const float4*)&F1c[vv * 64 + tx * 4];
            float av[16] = {a0.x, a0.y, a0.z, a0.w, a1.x, a1.y, a1.z, a1.w,
                            a2.x, a2.y, a2.z, a2.w, a3.x, a3.y, a3.z, a3.w};
            #pragma unroll
            for (int i = 0; i < 16; ++i) {
                acc[i][0] += av[i] * f.x;
                acc[i][1] += av[i] * f.y;
                acc[i][2] += av[i] * f.z;
                acc[i][3] += av[i] * f.w;
            }
        }
    }

    // ---- epilogue: scale by F0 (registers), reduce over u ----
    float c0r[8], s0r[8];
    {
        const float* cos0 = cosT + b * 8192;
        const float* sin0 = sinT + b * 8192;
        #pragma unroll
        for (int p = 0; p < 8; ++p) {
            int pos = w0 + tx * 4 + p;
            bool ok = pos < L_SZ;
            c0r[p] = ok ? cos0[pos] : 0.f;
            s0r[p] = ok ? sin0[pos] : 0.f;
        }
    }
    float zs[4] = {0.f, 0.f, 0.f, 0.f};
    int u0 = ty * 16;
    #pragma unroll
    for (int i = 0; i < 16; ++i) {
        int u = u0 + i;
        int t0 = u / 81; int r = u - t0 * 81;
        int t1 = r / 27; r -= t1 * 27;
        int t2 = r / 9;  r -= t2 * 9;
        int t3 = r / 3;  int t4 = r - t3 * 3;
        #pragma unroll
        for (int j = 0; j < 4; ++j) {
            float f = sel3(t0, c0r[j], s0r[j]) * sel3(t1, c0r[j + 1], s0r[j + 1])
                    * sel3(t2, c0r[j + 2], s0r[j + 2]) * sel3(t3, c0r[j + 3], s0r[j + 3])
                    * sel3(t4, c0r[j + 4], s0r[j + 4]);
            zs[j] += f * acc[i][j];   // acc rows for u>=243 are 0 (CT pad)
        }
    }
    // reduce over ty: 4 ty-groups in-wave, then 4 waves via LDS
    #pragma unroll
    for (int j = 0; j < 4; ++j) {
        float v = zs[j];
        v += __shfl_xor(v, 16, 64);
        v += __shfl_xor(v, 32, 64);
        zs[j] = v;
    }
    int wave = tid >> 6, lane = tid & 63;
    if (lane < 16) {
        #pragma unroll
        for (int j = 0; j < 4; ++j) partial[wave][lane][j] = zs[j];
    }
    __syncthreads();
    if (tid < 64) {
        int w = tid;                 // w = tx*4 + j
        if (w0 + w < NWIN) {
            int txo = w >> 2, j = w & 3;
            float z = partial[0][txo][j] + partial[1][txo][j]
                    + partial[2][txo][j] + partial[3][txo][j];
            out[b * NWIN + w0 + w] = z;
        }
    }
}

extern "C" void kernel_launch(void* const* d_in, const int* in_sizes, int n_in,
                              void* d_out, int out_size, void* d_ws, size_t ws_size,
                              hipStream_t stream) {
    const float* x     = (const float*)d_in[0];
    const float* E     = (const float*)d_in[1];
    const float* theta = (const float*)d_in[2];
    float* out = (float*)d_out;
    float* ws = (float*)d_ws;

    float* cosT = ws + COS_OFF;
    float* sinT = ws + SIN_OFF;
    float* Y    = ws + Y_OFF;
    float* M    = ws + M_OFF;
    float* CT   = ws + CT_OFF;
    float* Mx   = ws + EXTRA_OFF;

    // runtime-gated K-split factor (separate partial buffers, no atomics)
    size_t need4 = (size_t)(EXTRA_OFF + 3 * 1048576) * 4;
    size_t need2 = (size_t)(EXTRA_OFF + 1 * 1048576) * 4;
    int S = (ws_size >= need4) ? 4 : ((ws_size >= need2) ? 2 : 1);

    trig_ker<<<512, 256, 0, stream>>>(x, cosT, sinT);
    y_ker<<<2048, 256, 0, stream>>>(E, theta, Y);
    mgemm_ker<<<dim3(16, 16, S), 256, 0, stream>>>(E, Y, M, Mx);
    if (S > 1) sum_ker<<<1024, 256, 0, stream>>>(M, Mx, S);
    cwht_ker<<<1024, 256, 0, stream>>>(M, CT);
    main_ker<<<dim3(64, 16), 256, 0, stream>>>(cosT, sinT, CT, out);
}

// Round 4
// 122.810 us; speedup vs baseline: 3.5255x; 1.7902x over previous
//
#include <hip/hip_runtime.h>
#include <math.h>

// Problem constants
#define B_SZ   16
#define L_SZ   4096
#define NWIN   4092      // (4096-5)/1+1
#define U3     243       // 3^5
#define UPAD   256

// ws layout (float offsets)
#define COS_OFF 0
#define SIN_OFF 131072                    // 16*2*4096
#define Y_OFF   262144
#define M_OFF   (Y_OFF + 1048576)         // 1310720
#define CT_OFF  (M_OFF + 1048576)         // 2359296
#define APK_OFF (CT_OFF + 65536)          // 2424832  (C packed bf16 hi/lo = 16384 uint4)
#define EXTRA_OFF (APK_OFF + 65536)       // 2490368  (mgemm K-split partials)

typedef __attribute__((ext_vector_type(8))) __bf16 bf16x8;
typedef __attribute__((ext_vector_type(4))) float f32x4;

__device__ __forceinline__ float sel3(int t, float c, float s) {
    return t == 0 ? 1.0f : (t == 1 ? c : s);
}

// ---------------- trig tables ----------------
__global__ __launch_bounds__(256) void trig_ker(const float* __restrict__ x,
                                                float* __restrict__ cosT,
                                                float* __restrict__ sinT) {
    int idx = blockIdx.x * 256 + threadIdx.x;   // < 131072
    float v = x[idx];
    cosT[idx] = cosf(v);
    sinT[idx] = sinf(v);
}

// ---------------- Y = (G ⊗ I_512) E ----------------
__global__ __launch_bounds__(256) void y_ker(const float* __restrict__ E,
                                             const float* __restrict__ theta,
                                             float* __restrict__ Y) {
    int idx = blockIdx.x * 256 + threadIdx.x;   // < 524288
    float th = theta[0];
    float st, ct;
    __sincosf(th, &st, &ct);
    int r = idx >> 10, k = idx & 1023;
    float e0 = E[r * 1024 + k];
    float e1 = E[(512 + r) * 1024 + k];
    Y[r * 1024 + k]         =  ct * e0 - st * e1;
    Y[(512 + r) * 1024 + k] = -st * e0 - ct * e1;
}

// ---------------- M = E^T Y, K-split S into separate partials (no atomics) ----------------
__global__ __launch_bounds__(256, 2) void mgemm_ker(const float* __restrict__ E,
                                                    const float* __restrict__ Y,
                                                    float* __restrict__ M,
                                                    float* __restrict__ Mp_extra) {
    __shared__ float Es[16][64];
    __shared__ float Ys[16][64];
    int bj = blockIdx.x, bk = blockIdx.y, ks = blockIdx.z;
    int tid = threadIdx.x;
    int tx = tid & 15, ty = tid >> 4;
    int lr = tid >> 4, lc = (tid & 15) * 4;
    float acc[4][4];
    #pragma unroll
    for (int i = 0; i < 4; ++i)
        #pragma unroll
        for (int j = 0; j < 4; ++j) acc[i][j] = 0.f;

    int kchunk = 1024 / gridDim.z;
    int k0 = ks * kchunk;
    for (int d0 = k0; d0 < k0 + kchunk; d0 += 16) {
        float4 e = *(const float4*)&E[(d0 + lr) * 1024 + bj * 64 + lc];
        float4 y = *(const float4*)&Y[(d0 + lr) * 1024 + bk * 64 + lc];
        __syncthreads();
        *(float4*)&Es[lr][lc] = e;
        *(float4*)&Ys[lr][lc] = y;
        __syncthreads();
        #pragma unroll
        for (int dd = 0; dd < 16; ++dd) {
            float4 a = *(const float4*)&Es[dd][ty * 4];
            float4 bv = *(const float4*)&Ys[dd][tx * 4];
            acc[0][0] += a.x * bv.x; acc[0][1] += a.x * bv.y; acc[0][2] += a.x * bv.z; acc[0][3] += a.x * bv.w;
            acc[1][0] += a.y * bv.x; acc[1][1] += a.y * bv.y; acc[1][2] += a.y * bv.z; acc[1][3] += a.y * bv.w;
            acc[2][0] += a.z * bv.x; acc[2][1] += a.z * bv.y; acc[2][2] += a.z * bv.z; acc[2][3] += a.z * bv.w;
            acc[3][0] += a.w * bv.x; acc[3][1] += a.w * bv.y; acc[3][2] += a.w * bv.z; acc[3][3] += a.w * bv.w;
        }
    }
    float* dst = (ks == 0) ? M : (Mp_extra + (ks - 1) * 1048576);
    #pragma unroll
    for (int i = 0; i < 4; ++i) {
        float4 r = make_float4(acc[i][0], acc[i][1], acc[i][2], acc[i][3]);
        *(float4*)&dst[(bj * 64 + ty * 4 + i) * 1024 + bk * 64 + tx * 4] = r;
    }
}

__global__ __launch_bounds__(256) void sum_ker(float* __restrict__ M,
                                               const float* __restrict__ Mp_extra,
                                               int S) {
    int i = blockIdx.x * 256 + threadIdx.x;
    float4 v = ((const float4*)M)[i];
    for (int s = 1; s < S; ++s) {
        float4 p = ((const float4*)(Mp_extra + (s - 1) * 1048576))[i];
        v.x += p.x; v.y += p.y; v.z += p.z; v.w += p.w;
    }
    ((float4*)M)[i] = v;
}

// ---------------- C via WHT of generalized diagonals ----------------
__global__ __launch_bounds__(256) void cwht_ker(const float* __restrict__ M,
                                                float* __restrict__ CT) {
    __shared__ float D[1024];
    int mx = blockIdx.x;
    int tid = threadIdx.x;
    #pragma unroll
    for (int k = 0; k < 4; ++k) {
        int j = tid + k * 256;
        D[j] = M[j * 1024 + (j ^ mx)];
    }
    __syncthreads();
    for (int s = 0; s < 10; ++s) {
        #pragma unroll
        for (int k = 0; k < 2; ++k) {
            int p = tid + k * 256;
            int i = ((p >> s) << (s + 1)) | (p & ((1 << s) - 1));
            int j2 = i | (1 << s);
            float lo = D[i], hi = D[j2];
            D[i] = lo + hi;
            D[j2] = lo - hi;
        }
        __syncthreads();
    }
    for (int mz = tid; mz < 1024; mz += 256) {
        if (mz & mx) continue;
        int u = 0, v = 0;
        #pragma unroll
        for (int i = 0; i < 5; ++i) {
            int bit = 9 - i;
            int t = ((mx >> bit) & 1) ? 2 : (((mz >> bit) & 1) ? 1 : 0);
            u = u * 3 + t;
        }
        #pragma unroll
        for (int i = 5; i < 10; ++i) {
            int bit = 9 - i;
            int t = ((mx >> bit) & 1) ? 2 : (((mz >> bit) & 1) ? 1 : 0);
            v = v * 3 + t;
        }
        CT[v * UPAD + u] = D[mz] * (1.0f / 1024.0f);
    }
    if (mx == 0) {
        for (int e = tid; e < U3 * (UPAD - U3); e += 256) {
            int v = e / (UPAD - U3), q = e % (UPAD - U3);
            CT[v * UPAD + U3 + q] = 0.0f;
        }
        for (int e = tid; e < (256 - U3) * UPAD; e += 256) {
            CT[U3 * UPAD + e] = 0.0f;
        }
    }
}

// ---------------- pack C into MFMA A-fragment order, bf16 hi/lo ----------------
// Apk[idx], idx = (ut*8 + ks)*64 + lane: 8 bf16 = A[u = ut*16+(lane&15)][v = ks*32+(lane>>4)*8+j]
__global__ __launch_bounds__(256) void apack_ker(const float* __restrict__ CT,
                                                 uint4* __restrict__ Apk) {
    int idx = blockIdx.x * 256 + threadIdx.x;    // < 8192
    int l = idx & 63;
    int rest = idx >> 6;
    int ks = rest & 7, ut = rest >> 3;
    int u = ut * 16 + (l & 15);
    int vb = ks * 32 + (l >> 4) * 8;
    unsigned hw[4], lw[4];
    #pragma unroll
    for (int j = 0; j < 8; ++j) {
        float x = CT[(vb + j) * UPAD + u];
        unsigned ux = __float_as_uint(x);
        unsigned hh = ux >> 16;                      // truncation split: lo absorbs the error
        float hf = __uint_as_float(hh << 16);
        float lf = x - hf;
        unsigned ll = __float_as_uint(lf) >> 16;
        if (j & 1) { hw[j >> 1] |= hh << 16; lw[j >> 1] |= ll << 16; }
        else       { hw[j >> 1] = hh;        lw[j >> 1] = ll; }
    }
    Apk[idx]        = make_uint4(hw[0], hw[1], hw[2], hw[3]);
    Apk[8192 + idx] = make_uint4(lw[0], lw[1], lw[2], lw[3]);
}

// ---------------- main: 64 windows/block, MFMA 16x16x32 bf16 3-term split ----------------
__global__ __launch_bounds__(256, 2) void main_ker(const float* __restrict__ cosT,
                                                   const float* __restrict__ sinT,
                                                   const uint4* __restrict__ Apk,
                                                   float* __restrict__ out) {
    __shared__ float trg[4][68];                       // c1,s1,c0,s0 rows
    __shared__ __align__(16) unsigned char arena[34816];
    unsigned short* F1h = (unsigned short*)arena;            // 16*65*8 shorts = 16640 B
    unsigned short* F1l = (unsigned short*)(arena + 16640);  // 16640 B
    float* F0  = (float*)arena;                              // 256*33*4 = 33792 B (after MFMA)
    float* red = (float*)(arena + 33792);                    // 16*16*4 = 1024 B

    int tid = threadIdx.x;
    int w0 = blockIdx.x * 64;
    int b  = blockIdx.y;
    int lane = tid & 63;
    int wave = tid >> 6;

    // stage trig rows (both channels)
    for (int p = tid; p < 68; p += 256) {
        int pos = w0 + p;
        bool ok = pos < L_SZ;
        trg[0][p] = ok ? cosT[b * 8192 + 4096 + pos] : 0.f;
        trg[1][p] = ok ? sinT[b * 8192 + 4096 + pos] : 0.f;
        trg[2][p] = ok ? cosT[b * 8192 + pos] : 0.f;
        trg[3][p] = ok ? sinT[b * 8192 + pos] : 0.f;
    }

    f32x4 acc[4][4];
    #pragma unroll
    for (int ut = 0; ut < 4; ++ut)
        #pragma unroll
        for (int wt = 0; wt < 4; ++wt)
            acc[ut][wt] = (f32x4){0.f, 0.f, 0.f, 0.f};

    __syncthreads();

    // per-thread ch1 trig registers (builder role: w = tid&63, v-range by wave)
    int wb = tid & 63;
    float c1r[5], s1r[5];
    #pragma unroll
    for (int k = 0; k < 5; ++k) { c1r[k] = trg[0][wb + k]; s1r[k] = trg[1][wb + k]; }

    const uint4* Ahi = Apk;
    const uint4* Alo = Apk + 8192;

    #pragma unroll 1
    for (int h = 0; h < 2; ++h) {
        // ---- build F1 half h into LDS (packed bf16x8 hi/lo, 65-unit padded rows) ----
        {
            int gv = h * 128 + wave * 32;               // global v base (wave-uniform)
            int t0 = gv / 81; int rr = gv - t0 * 81;
            int t1 = rr / 27; rr -= t1 * 27;
            int t2 = rr / 9;  rr -= t2 * 9;
            int t3 = rr / 3;  int t4 = rr - t3 * 3;
            float g0 = sel3(t0, c1r[0], s1r[0]);
            float g1 = sel3(t1, c1r[1], s1r[1]);
            float g2 = sel3(t2, c1r[2], s1r[2]);
            float g3 = sel3(t3, c1r[3], s1r[3]);
            float p01 = g0 * g1, p012 = p01 * g2, p0123 = p012 * g3;
            #pragma unroll
            for (int p8 = 0; p8 < 4; ++p8) {
                unsigned hw[4], lw[4];
                #pragma unroll
                for (int i = 0; i < 8; ++i) {
                    int gvv = gv + p8 * 8 + i;
                    float val = p0123 * sel3(t4, c1r[4], s1r[4]);
                    if (gvv >= U3) val = 0.f;
                    unsigned ux = __float_as_uint(val);
                    unsigned hh = ux >> 16;
                    float hf = __uint_as_float(hh << 16);
                    float lf = val - hf;
                    unsigned ll = __float_as_uint(lf) >> 16;
                    if (i & 1) { hw[i >> 1] |= hh << 16; lw[i >> 1] |= ll << 16; }
                    else       { hw[i >> 1] = hh;        lw[i >> 1] = ll; }
                    // increment base-3 digits (wave-uniform carries)
                    if (++t4 == 3) { t4 = 0;
                        if (++t3 == 3) { t3 = 0;
                            if (++t2 == 3) { t2 = 0;
                                if (++t1 == 3) { t1 = 0; ++t0; g0 = sel3(t0, c1r[0], s1r[0]); }
                                g1 = sel3(t1, c1r[1], s1r[1]); p01 = g0 * g1;
                            }
                            g2 = sel3(t2, c1r[2], s1r[2]); p012 = p01 * g2;
                        }
                        g3 = sel3(t3, c1r[3], s1r[3]); p0123 = p012 * g3;
                    }
                }
                int vp = wave * 4 + p8;
                *(uint4*)&F1h[(vp * 65 + wb) * 8] = make_uint4(hw[0], hw[1], hw[2], hw[3]);
                *(uint4*)&F1l[(vp * 65 + wb) * 8] = make_uint4(lw[0], lw[1], lw[2], lw[3]);
            }
        }
        __syncthreads();

        // ---- MFMA over this half's 4 K-steps ----
        #pragma unroll
        for (int kl = 0; kl < 4; ++kl) {
            int ks = h * 4 + kl;
            uint4 a_h[4], a_l[4], b_h[4], b_l[4];
            #pragma unroll
            for (int ut = 0; ut < 4; ++ut) {
                int idx = ((wave * 4 + ut) * 8 + ks) * 64 + lane;
                a_h[ut] = Ahi[idx];
                a_l[ut] = Alo[idx];
            }
            int vp = kl * 4 + (lane >> 4);
            #pragma unroll
            for (int wt = 0; wt < 4; ++wt) {
                int off = (vp * 65 + wt * 16 + (lane & 15)) * 8;
                b_h[wt] = *(const uint4*)&F1h[off];
                b_l[wt] = *(const uint4*)&F1l[off];
            }
            #pragma unroll
            for (int ut = 0; ut < 4; ++ut) {
                bf16x8 ah = __builtin_bit_cast(bf16x8, a_h[ut]);
                bf16x8 al = __builtin_bit_cast(bf16x8, a_l[ut]);
                #pragma unroll
                for (int wt = 0; wt < 4; ++wt) {
                    bf16x8 bh = __builtin_bit_cast(bf16x8, b_h[wt]);
                    bf16x8 bl = __builtin_bit_cast(bf16x8, b_l[wt]);
                    acc[ut][wt] = __builtin_amdgcn_mfma_f32_16x16x32_bf16(ah, bh, acc[ut][wt], 0, 0, 0);
                    acc[ut][wt] = __builtin_amdgcn_mfma_f32_16x16x32_bf16(ah, bl, acc[ut][wt], 0, 0, 0);
                    acc[ut][wt] = __builtin_amdgcn_mfma_f32_16x16x32_bf16(al, bh, acc[ut][wt], 0, 0, 0);
                }
            }
        }
        __syncthreads();
    }

    // ---- epilogue: z[w] = sum_u F0[u,w] * G[u,w], F0 fp32 via LDS, two w-halves ----
    float zcol[4] = {0.f, 0.f, 0.f, 0.f};
    #pragma unroll 1
    for (int hp = 0; hp < 2; ++hp) {
        {
            int wl = tid & 31;                    // local w
            int q = tid >> 5;                     // u-base group 0..7
            float c0r[5], s0r[5];
            #pragma unroll
            for (int k = 0; k < 5; ++k) {
                c0r[k] = trg[2][hp * 32 + wl + k];
                s0r[k] = trg[3][hp * 32 + wl + k];
            }
            int ub = q * 32;
            int t0 = ub / 81; int rr = ub - t0 * 81;
            int t1 = rr / 27; rr -= t1 * 27;
            int t2 = rr / 9;  rr -= t2 * 9;
            int t3 = rr / 3;  int t4 = rr - t3 * 3;
            float g0 = sel3(t0, c0r[0], s0r[0]);
            float g1 = sel3(t1, c0r[1], s0r[1]);
            float g2 = sel3(t2, c0r[2], s0r[2]);
            float g3 = sel3(t3, c0r[3], s0r[3]);
            float p01 = g0 * g1, p012 = p01 * g2, p0123 = p012 * g3;
            #pragma unroll
            for (int p8 = 0; p8 < 4; ++p8) {
                #pragma unroll
                for (int i = 0; i < 8; ++i) {
                    int u = ub + p8 * 8 + i;
                    float val = p0123 * sel3(t4, c0r[4], s0r[4]);
                    if (u >= U3) val = 0.f;
                    F0[u * 33 + wl] = val;
                    if (++t4 == 3) { t4 = 0;
                        if (++t3 == 3) { t3 = 0;
                            if (++t2 == 3) { t2 = 0;
                                if (++t1 == 3) { t1 = 0; ++t0; g0 = sel3(t0, c0r[0], s0r[0]); }
                                g1 = sel3(t1, c0r[1], s0r[1]); p01 = g0 * g1;
                            }
                            g2 = sel3(t2, c0r[2], s0r[2]); p012 = p01 * g2;
                        }
                        g3 = sel3(t3, c0r[3], s0r[3]); p0123 = p012 * g3;
                    }
                }
            }
        }
        __syncthreads();
        #pragma unroll
        for (int ut = 0; ut < 4; ++ut) {
            #pragma unroll
            for (int r = 0; r < 4; ++r) {
                int u = wave * 64 + ut * 16 + ((lane >> 4) << 2) + r;
                float f0a = F0[u * 33 + (lane & 15)];
                float f0b = F0[u * 33 + 16 + (lane & 15)];
                zcol[hp * 2 + 0] += f0a * acc[ut][hp * 2 + 0][r];
                zcol[hp * 2 + 1] += f0b * acc[ut][hp * 2 + 1][r];
            }
        }
        __syncthreads();
    }

    // ---- reduce over u-groups: in-wave (lane>>4), then across 4 waves via LDS ----
    #pragma unroll
    for (int wt = 0; wt < 4; ++wt) {
        float v = zcol[wt];
        v += __shfl_xor(v, 16, 64);
        v += __shfl_xor(v, 32, 64);
        if ((lane >> 4) == 0) red[(wave * 4 + wt) * 16 + lane] = v;
    }
    __syncthreads();
    if (tid < 64) {
        int wt = tid >> 4, c = tid & 15;
        float z = red[(0 * 4 + wt) * 16 + c] + red[(1 * 4 + wt) * 16 + c]
                + red[(2 * 4 + wt) * 16 + c] + red[(3 * 4 + wt) * 16 + c];
        int w = wt * 16 + c;
        if (w0 + w < NWIN) out[b * NWIN + w0 + w] = z;
    }
}

extern "C" void kernel_launch(void* const* d_in, const int* in_sizes, int n_in,
                              void* d_out, int out_size, void* d_ws, size_t ws_size,
                              hipStream_t stream) {
    const float* x     = (const float*)d_in[0];
    const float* E     = (const float*)d_in[1];
    const float* theta = (const float*)d_in[2];
    float* out = (float*)d_out;
    float* ws = (float*)d_ws;

    float* cosT = ws + COS_OFF;
    float* sinT = ws + SIN_OFF;
    float* Y    = ws + Y_OFF;
    float* M    = ws + M_OFF;
    float* CT   = ws + CT_OFF;
    uint4* Apk  = (uint4*)(ws + APK_OFF);
    float* Mx   = ws + EXTRA_OFF;

    size_t need4 = (size_t)(EXTRA_OFF + 3 * 1048576) * 4;
    size_t need2 = (size_t)(EXTRA_OFF + 1 * 1048576) * 4;
    int S = (ws_size >= need4) ? 4 : ((ws_size >= need2) ? 2 : 1);

    trig_ker<<<512, 256, 0, stream>>>(x, cosT, sinT);
    y_ker<<<2048, 256, 0, stream>>>(E, theta, Y);
    mgemm_ker<<<dim3(16, 16, S), 256, 0, stream>>>(E, Y, M, Mx);
    if (S > 1) sum_ker<<<1024, 256, 0, stream>>>(M, Mx, S);
    cwht_ker<<<1024, 256, 0, stream>>>(M, CT);
    apack_ker<<<32, 256, 0, stream>>>(CT, Apk);
    main_ker<<<dim3(64, 16), 256, 0, stream>>>(cosT, sinT, Apk, out);
}

// Round 5
// 99.223 us; speedup vs baseline: 4.3636x; 1.2377x over previous
//
#include <hip/hip_runtime.h>
#include <math.h>

// Problem constants
#define B_SZ   16
#define L_SZ   4096
#define NWIN   4092      // (4096-5)/1+1
#define U3     243       // 3^5
#define UPAD   256

// ws layout (float offsets)
#define COS_OFF 0
#define SIN_OFF 131072                    // 16*2*4096
#define Y_OFF   262144
#define M_OFF   (Y_OFF + 1048576)         // 1310720
#define CT_OFF  (M_OFF + 1048576)         // 2359296
#define APK_OFF (CT_OFF + 65536)          // 2424832  (C packed bf16 hi/lo = 16384 uint4)
#define EXTRA_OFF (APK_OFF + 65536)       // 2490368  (mgemm K-split partials)

typedef __attribute__((ext_vector_type(8))) __bf16 bf16x8;
typedef __attribute__((ext_vector_type(4))) float f32x4;

__device__ __forceinline__ float sel3(int t, float c, float s) {
    return t == 0 ? 1.0f : (t == 1 ? c : s);
}

// ---------------- trig tables ----------------
__global__ __launch_bounds__(256) void trig_ker(const float* __restrict__ x,
                                                float* __restrict__ cosT,
                                                float* __restrict__ sinT) {
    int idx = blockIdx.x * 256 + threadIdx.x;   // < 131072
    float v = x[idx];
    cosT[idx] = cosf(v);
    sinT[idx] = sinf(v);
}

// ---------------- Y = (G ⊗ I_512) E ----------------
__global__ __launch_bounds__(256) void y_ker(const float* __restrict__ E,
                                             const float* __restrict__ theta,
                                             float* __restrict__ Y) {
    int idx = blockIdx.x * 256 + threadIdx.x;   // < 524288
    float th = theta[0];
    float st, ct;
    __sincosf(th, &st, &ct);
    int r = idx >> 10, k = idx & 1023;
    float e0 = E[r * 1024 + k];
    float e1 = E[(512 + r) * 1024 + k];
    Y[r * 1024 + k]         =  ct * e0 - st * e1;
    Y[(512 + r) * 1024 + k] = -st * e0 - ct * e1;
}

// ---------------- M = E^T Y, K-split S into separate partials (no atomics) ----------------
__global__ __launch_bounds__(256, 2) void mgemm_ker(const float* __restrict__ E,
                                                    const float* __restrict__ Y,
                                                    float* __restrict__ M,
                                                    float* __restrict__ Mp_extra) {
    __shared__ float Es[16][64];
    __shared__ float Ys[16][64];
    int bj = blockIdx.x, bk = blockIdx.y, ks = blockIdx.z;
    int tid = threadIdx.x;
    int tx = tid & 15, ty = tid >> 4;
    int lr = tid >> 4, lc = (tid & 15) * 4;
    float acc[4][4];
    #pragma unroll
    for (int i = 0; i < 4; ++i)
        #pragma unroll
        for (int j = 0; j < 4; ++j) acc[i][j] = 0.f;

    int kchunk = 1024 / gridDim.z;
    int k0 = ks * kchunk;
    for (int d0 = k0; d0 < k0 + kchunk; d0 += 16) {
        float4 e = *(const float4*)&E[(d0 + lr) * 1024 + bj * 64 + lc];
        float4 y = *(const float4*)&Y[(d0 + lr) * 1024 + bk * 64 + lc];
        __syncthreads();
        *(float4*)&Es[lr][lc] = e;
        *(float4*)&Ys[lr][lc] = y;
        __syncthreads();
        #pragma unroll
        for (int dd = 0; dd < 16; ++dd) {
            float4 a = *(const float4*)&Es[dd][ty * 4];
            float4 bv = *(const float4*)&Ys[dd][tx * 4];
            acc[0][0] += a.x * bv.x; acc[0][1] += a.x * bv.y; acc[0][2] += a.x * bv.z; acc[0][3] += a.x * bv.w;
            acc[1][0] += a.y * bv.x; acc[1][1] += a.y * bv.y; acc[1][2] += a.y * bv.z; acc[1][3] += a.y * bv.w;
            acc[2][0] += a.z * bv.x; acc[2][1] += a.z * bv.y; acc[2][2] += a.z * bv.z; acc[2][3] += a.z * bv.w;
            acc[3][0] += a.w * bv.x; acc[3][1] += a.w * bv.y; acc[3][2] += a.w * bv.z; acc[3][3] += a.w * bv.w;
        }
    }
    float* dst = (ks == 0) ? M : (Mp_extra + (ks - 1) * 1048576);
    #pragma unroll
    for (int i = 0; i < 4; ++i) {
        float4 r = make_float4(acc[i][0], acc[i][1], acc[i][2], acc[i][3]);
        *(float4*)&dst[(bj * 64 + ty * 4 + i) * 1024 + bk * 64 + tx * 4] = r;
    }
}

__global__ __launch_bounds__(256) void sum_ker(float* __restrict__ M,
                                               const float* __restrict__ Mp_extra,
                                               int S) {
    int i = blockIdx.x * 256 + threadIdx.x;
    float4 v = ((const float4*)M)[i];
    for (int s = 1; s < S; ++s) {
        float4 p = ((const float4*)(Mp_extra + (s - 1) * 1048576))[i];
        v.x += p.x; v.y += p.y; v.z += p.z; v.w += p.w;
    }
    ((float4*)M)[i] = v;
}

// ---------------- C via WHT of generalized diagonals ----------------
__global__ __launch_bounds__(256) void cwht_ker(const float* __restrict__ M,
                                                float* __restrict__ CT) {
    __shared__ float D[1024];
    int mx = blockIdx.x;
    int tid = threadIdx.x;
    #pragma unroll
    for (int k = 0; k < 4; ++k) {
        int j = tid + k * 256;
        D[j] = M[j * 1024 + (j ^ mx)];
    }
    __syncthreads();
    for (int s = 0; s < 10; ++s) {
        #pragma unroll
        for (int k = 0; k < 2; ++k) {
            int p = tid + k * 256;
            int i = ((p >> s) << (s + 1)) | (p & ((1 << s) - 1));
            int j2 = i | (1 << s);
            float lo = D[i], hi = D[j2];
            D[i] = lo + hi;
            D[j2] = lo - hi;
        }
        __syncthreads();
    }
    for (int mz = tid; mz < 1024; mz += 256) {
        if (mz & mx) continue;
        int u = 0, v = 0;
        #pragma unroll
        for (int i = 0; i < 5; ++i) {
            int bit = 9 - i;
            int t = ((mx >> bit) & 1) ? 2 : (((mz >> bit) & 1) ? 1 : 0);
            u = u * 3 + t;
        }
        #pragma unroll
        for (int i = 5; i < 10; ++i) {
            int bit = 9 - i;
            int t = ((mx >> bit) & 1) ? 2 : (((mz >> bit) & 1) ? 1 : 0);
            v = v * 3 + t;
        }
        CT[v * UPAD + u] = D[mz] * (1.0f / 1024.0f);
    }
    if (mx == 0) {
        for (int e = tid; e < U3 * (UPAD - U3); e += 256) {
            int v = e / (UPAD - U3), q = e % (UPAD - U3);
            CT[v * UPAD + U3 + q] = 0.0f;
        }
        for (int e = tid; e < (256 - U3) * UPAD; e += 256) {
            CT[U3 * UPAD + e] = 0.0f;
        }
    }
}

// ---------------- pack C into MFMA A-fragment order, bf16 hi/lo ----------------
__global__ __launch_bounds__(256) void apack_ker(const float* __restrict__ CT,
                                                 uint4* __restrict__ Apk) {
    int idx = blockIdx.x * 256 + threadIdx.x;    // < 8192
    int l = idx & 63;
    int rest = idx >> 6;
    int ks = rest & 7, ut = rest >> 3;
    int u = ut * 16 + (l & 15);
    int vb = ks * 32 + (l >> 4) * 8;
    unsigned hw[4], lw[4];
    #pragma unroll
    for (int j = 0; j < 8; ++j) {
        float x = CT[(vb + j) * UPAD + u];
        unsigned ux = __float_as_uint(x);
        unsigned hh = ux >> 16;                      // truncation split: lo absorbs the error
        float hf = __uint_as_float(hh << 16);
        float lf = x - hf;
        unsigned ll = __float_as_uint(lf) >> 16;
        if (j & 1) { hw[j >> 1] |= hh << 16; lw[j >> 1] |= ll << 16; }
        else       { hw[j >> 1] = hh;        lw[j >> 1] = ll; }
    }
    Apk[idx]        = make_uint4(hw[0], hw[1], hw[2], hw[3]);
    Apk[8192 + idx] = make_uint4(lw[0], lw[1], lw[2], lw[3]);
}

// ---------------- main: 64 windows/block, MFMA 16x16x32 bf16 3-term split ----------------
__global__ __launch_bounds__(256, 2) void main_ker(const float* __restrict__ cosT,
                                                   const float* __restrict__ sinT,
                                                   const uint4* __restrict__ Apk,
                                                   float* __restrict__ out) {
    __shared__ float trg[4][68];                       // c1,s1,c0,s0 rows
    __shared__ __align__(16) unsigned char arena[34816];
    unsigned short* F1h = (unsigned short*)arena;            // 16*65*8 shorts = 16640 B
    unsigned short* F1l = (unsigned short*)(arena + 16640);  // 16640 B
    float* F0  = (float*)arena;                              // 256*33*4 = 33792 B (after MFMA)
    float* red = (float*)(arena + 33792);                    // 16*16*4 = 1024 B

    int tid = threadIdx.x;
    int w0 = blockIdx.x * 64;
    int b  = blockIdx.y;
    int lane = tid & 63;
    int wave = tid >> 6;

    // stage trig rows (both channels)
    for (int p = tid; p < 68; p += 256) {
        int pos = w0 + p;
        bool ok = pos < L_SZ;
        trg[0][p] = ok ? cosT[b * 8192 + 4096 + pos] : 0.f;
        trg[1][p] = ok ? sinT[b * 8192 + 4096 + pos] : 0.f;
        trg[2][p] = ok ? cosT[b * 8192 + pos] : 0.f;
        trg[3][p] = ok ? sinT[b * 8192 + pos] : 0.f;
    }

    f32x4 acc[4][4];
    #pragma unroll
    for (int ut = 0; ut < 4; ++ut)
        #pragma unroll
        for (int wt = 0; wt < 4; ++wt)
            acc[ut][wt] = (f32x4){0.f, 0.f, 0.f, 0.f};

    __syncthreads();

    // per-thread ch1 trig registers (builder role: w = tid&63, v-range by wave)
    int wb = tid & 63;
    float c1r[5], s1r[5];
    #pragma unroll
    for (int k = 0; k < 5; ++k) { c1r[k] = trg[0][wb + k]; s1r[k] = trg[1][wb + k]; }

    const uint4* Ahi = Apk;
    const uint4* Alo = Apk + 8192;

    #pragma unroll 1
    for (int h = 0; h < 2; ++h) {
        // ---- build F1 half h into LDS (packed bf16x8 hi/lo, 65-unit padded rows) ----
        {
            int gv = h * 128 + wave * 32;               // global v base (wave-uniform)
            int t0 = gv / 81; int rr = gv - t0 * 81;
            int t1 = rr / 27; rr -= t1 * 27;
            int t2 = rr / 9;  rr -= t2 * 9;
            int t3 = rr / 3;  int t4 = rr - t3 * 3;
            float g0 = sel3(t0, c1r[0], s1r[0]);
            float g1 = sel3(t1, c1r[1], s1r[1]);
            float g2 = sel3(t2, c1r[2], s1r[2]);
            float g3 = sel3(t3, c1r[3], s1r[3]);
            float p01 = g0 * g1, p012 = p01 * g2, p0123 = p012 * g3;
            #pragma unroll
            for (int p8 = 0; p8 < 4; ++p8) {
                unsigned hw[4], lw[4];
                #pragma unroll
                for (int i = 0; i < 8; ++i) {
                    int gvv = gv + p8 * 8 + i;
                    float val = p0123 * sel3(t4, c1r[4], s1r[4]);
                    if (gvv >= U3) val = 0.f;
                    unsigned ux = __float_as_uint(val);
                    unsigned hh = ux >> 16;
                    float hf = __uint_as_float(hh << 16);
                    float lf = val - hf;
                    unsigned ll = __float_as_uint(lf) >> 16;
                    if (i & 1) { hw[i >> 1] |= hh << 16; lw[i >> 1] |= ll << 16; }
                    else       { hw[i >> 1] = hh;        lw[i >> 1] = ll; }
                    // increment base-3 digits (wave-uniform carries)
                    if (++t4 == 3) { t4 = 0;
                        if (++t3 == 3) { t3 = 0;
                            if (++t2 == 3) { t2 = 0;
                                if (++t1 == 3) { t1 = 0; ++t0; g0 = sel3(t0, c1r[0], s1r[0]); }
                                g1 = sel3(t1, c1r[1], s1r[1]); p01 = g0 * g1;
                            }
                            g2 = sel3(t2, c1r[2], s1r[2]); p012 = p01 * g2;
                        }
                        g3 = sel3(t3, c1r[3], s1r[3]); p0123 = p012 * g3;
                    }
                }
                int vp = wave * 4 + p8;
                *(uint4*)&F1h[(vp * 65 + wb) * 8] = make_uint4(hw[0], hw[1], hw[2], hw[3]);
                *(uint4*)&F1l[(vp * 65 + wb) * 8] = make_uint4(lw[0], lw[1], lw[2], lw[3]);
            }
        }
        __syncthreads();

        // ---- MFMA over this half's 4 K-steps ----
        #pragma unroll
        for (int kl = 0; kl < 4; ++kl) {
            int ks = h * 4 + kl;
            uint4 a_h[4], a_l[4], b_h[4], b_l[4];
            #pragma unroll
            for (int ut = 0; ut < 4; ++ut) {
                int idx = ((wave * 4 + ut) * 8 + ks) * 64 + lane;
                a_h[ut] = Ahi[idx];
                a_l[ut] = Alo[idx];
            }
            int vp = kl * 4 + (lane >> 4);
            #pragma unroll
            for (int wt = 0; wt < 4; ++wt) {
                int off = (vp * 65 + wt * 16 + (lane & 15)) * 8;
                b_h[wt] = *(const uint4*)&F1h[off];
                b_l[wt] = *(const uint4*)&F1l[off];
            }
            #pragma unroll
            for (int ut = 0; ut < 4; ++ut) {
                bf16x8 ah = __builtin_bit_cast(bf16x8, a_h[ut]);
                bf16x8 al = __builtin_bit_cast(bf16x8, a_l[ut]);
                #pragma unroll
                for (int wt = 0; wt < 4; ++wt) {
                    bf16x8 bh = __builtin_bit_cast(bf16x8, b_h[wt]);
                    bf16x8 bl = __builtin_bit_cast(bf16x8, b_l[wt]);
                    acc[ut][wt] = __builtin_amdgcn_mfma_f32_16x16x32_bf16(ah, bh, acc[ut][wt], 0, 0, 0);
                    acc[ut][wt] = __builtin_amdgcn_mfma_f32_16x16x32_bf16(ah, bl, acc[ut][wt], 0, 0, 0);
                    acc[ut][wt] = __builtin_amdgcn_mfma_f32_16x16x32_bf16(al, bh, acc[ut][wt], 0, 0, 0);
                }
            }
        }
        __syncthreads();
    }

    // ---- epilogue: z[w] = sum_u F0[u,w] * G[u,w] — hp FULLY UNROLLED so acc
    //      stays statically indexed (rule #20: runtime index -> scratch spill) ----
    float zcol[4] = {0.f, 0.f, 0.f, 0.f};
    #pragma unroll
    for (int hp = 0; hp < 2; ++hp) {
        {
            int wl = tid & 31;                    // local w
            int q = tid >> 5;                     // u-base group 0..7
            float c0r[5], s0r[5];
            #pragma unroll
            for (int k = 0; k < 5; ++k) {
                c0r[k] = trg[2][hp * 32 + wl + k];
                s0r[k] = trg[3][hp * 32 + wl + k];
            }
            int ub = q * 32;
            int t0 = ub / 81; int rr = ub - t0 * 81;
            int t1 = rr / 27; rr -= t1 * 27;
            int t2 = rr / 9;  rr -= t2 * 9;
            int t3 = rr / 3;  int t4 = rr - t3 * 3;
            float g0 = sel3(t0, c0r[0], s0r[0]);
            float g1 = sel3(t1, c0r[1], s0r[1]);
            float g2 = sel3(t2, c0r[2], s0r[2]);
            float g3 = sel3(t3, c0r[3], s0r[3]);
            float p01 = g0 * g1, p012 = p01 * g2, p0123 = p012 * g3;
            #pragma unroll
            for (int p8 = 0; p8 < 4; ++p8) {
                #pragma unroll
                for (int i = 0; i < 8; ++i) {
                    int u = ub + p8 * 8 + i;
                    float val = p0123 * sel3(t4, c0r[4], s0r[4]);
                    if (u >= U3) val = 0.f;
                    F0[u * 33 + wl] = val;
                    if (++t4 == 3) { t4 = 0;
                        if (++t3 == 3) { t3 = 0;
                            if (++t2 == 3) { t2 = 0;
                                if (++t1 == 3) { t1 = 0; ++t0; g0 = sel3(t0, c0r[0], s0r[0]); }
                                g1 = sel3(t1, c0r[1], s0r[1]); p01 = g0 * g1;
                            }
                            g2 = sel3(t2, c0r[2], s0r[2]); p012 = p01 * g2;
                        }
                        g3 = sel3(t3, c0r[3], s0r[3]); p0123 = p012 * g3;
                    }
                }
            }
        }
        __syncthreads();
        #pragma unroll
        for (int ut = 0; ut < 4; ++ut) {
            #pragma unroll
            for (int r = 0; r < 4; ++r) {
                int u = wave * 64 + ut * 16 + ((lane >> 4) << 2) + r;
                float f0a = F0[u * 33 + (lane & 15)];
                float f0b = F0[u * 33 + 16 + (lane & 15)];
                zcol[hp * 2 + 0] += f0a * acc[ut][hp * 2 + 0][r];
                zcol[hp * 2 + 1] += f0b * acc[ut][hp * 2 + 1][r];
            }
        }
        __syncthreads();
    }

    // ---- reduce over u-groups: in-wave (lane>>4), then across 4 waves via LDS ----
    #pragma unroll
    for (int wt = 0; wt < 4; ++wt) {
        float v = zcol[wt];
        v += __shfl_xor(v, 16, 64);
        v += __shfl_xor(v, 32, 64);
        if ((lane >> 4) == 0) red[(wave * 4 + wt) * 16 + lane] = v;
    }
    __syncthreads();
    if (tid < 64) {
        int wt = tid >> 4, c = tid & 15;
        float z = red[(0 * 4 + wt) * 16 + c] + red[(1 * 4 + wt) * 16 + c]
                + red[(2 * 4 + wt) * 16 + c] + red[(3 * 4 + wt) * 16 + c];
        int w = wt * 16 + c;
        if (w0 + w < NWIN) out[b * NWIN + w0 + w] = z;
    }
}

extern "C" void kernel_launch(void* const* d_in, const int* in_sizes, int n_in,
                              void* d_out, int out_size, void* d_ws, size_t ws_size,
                              hipStream_t stream) {
    const float* x     = (const float*)d_in[0];
    const float* E     = (const float*)d_in[1];
    const float* theta = (const float*)d_in[2];
    float* out = (float*)d_out;
    float* ws = (float*)d_ws;

    float* cosT = ws + COS_OFF;
    float* sinT = ws + SIN_OFF;
    float* Y    = ws + Y_OFF;
    float* M    = ws + M_OFF;
    float* CT   = ws + CT_OFF;
    uint4* Apk  = (uint4*)(ws + APK_OFF);
    float* Mx   = ws + EXTRA_OFF;

    size_t need4 = (size_t)(EXTRA_OFF + 3 * 1048576) * 4;
    size_t need2 = (size_t)(EXTRA_OFF + 1 * 1048576) * 4;
    int S = (ws_size >= need4) ? 4 : ((ws_size >= need2) ? 2 : 1);

    trig_ker<<<512, 256, 0, stream>>>(x, cosT, sinT);
    y_ker<<<2048, 256, 0, stream>>>(E, theta, Y);
    mgemm_ker<<<dim3(16, 16, S), 256, 0, stream>>>(E, Y, M, Mx);
    if (S > 1) sum_ker<<<1024, 256, 0, stream>>>(M, Mx, S);
    cwht_ker<<<1024, 256, 0, stream>>>(M, CT);
    apack_ker<<<32, 256, 0, stream>>>(CT, Apk);
    main_ker<<<dim3(64, 16), 256, 0, stream>>>(cosT, sinT, Apk, out);
}